// Round 6
// baseline (300.041 us; speedup 1.0000x reference)
//
#include <hip/hip_runtime.h>

#define HH 192
#define WW 256
#define NPIX (HH*WW)   // 49152
#define NSEG (NPIX/64) // 768

__device__ __forceinline__ float lrelu(float v) { return v > 0.0f ? v : 0.01f * v; }

// ============================================================================
// k_fused1: y=0 -> x_t = lrelu(Wcl1@X)^T-stored; y=1 -> r_t (Wr1);
//           y=2 -> full mask branch.
// ============================================================================
__global__ __launch_bounds__(256, 3) void k_fused1(
    const float* __restrict__ X,
    const float* __restrict__ Wcl1, const float* __restrict__ bcl1,
    const float* __restrict__ Wr1,  const float* __restrict__ br1,
    const float* __restrict__ Wm1,  const float* __restrict__ bm1,
    const float* __restrict__ Wm2,  const float* __restrict__ bm2,
    const float* __restrict__ Wm3,  const float* __restrict__ bm3,
    float* __restrict__ x_t, float* __restrict__ r_t,
    float* __restrict__ out)
{
    __shared__ float As[16][132];
    __shared__ float Ws[16][132];
    __shared__ float m1buf[128][33];
    const int tid = threadIdx.x;
    const int q0  = blockIdx.x * 128;

    if (blockIdx.y == 2) {
        // ---------------- mask path ----------------
        const int tc = tid & 31;
        const int tr = tid >> 5;
        float acc[4][4];
        #pragma unroll
        for (int i = 0; i < 4; ++i)
            #pragma unroll
            for (int j = 0; j < 4; ++j)
                acc[i][j] = bm1[tr * 4 + j];

        for (int k0 = 0; k0 < 128; k0 += 16) {
            #pragma unroll
            for (int p = 0; p < 2; ++p) {
                int lin = p * 1024 + tid * 4;
                int kk = lin >> 7, px = lin & 127;
                float4 v = *(const float4*)(X + (k0 + kk) * NPIX + q0 + px);
                *(float4*)(&As[kk][px]) = v;
            }
            if (tid < 128) {
                int row = tid >> 2, kc = (tid & 3) * 4;
                float4 v = *(const float4*)(Wm1 + row * 128 + k0 + kc);
                Ws[kc + 0][row] = v.x; Ws[kc + 1][row] = v.y;
                Ws[kc + 2][row] = v.z; Ws[kc + 3][row] = v.w;
            }
            __syncthreads();
            #pragma unroll
            for (int kk = 0; kk < 16; ++kk) {
                float4 a = *(const float4*)(&As[kk][tc * 4]);
                float4 w = *(const float4*)(&Ws[kk][tr * 4]);
                float av[4] = {a.x,a.y,a.z,a.w};
                float wv[4] = {w.x,w.y,w.z,w.w};
                #pragma unroll
                for (int i = 0; i < 4; ++i)
                    #pragma unroll
                    for (int j = 0; j < 4; ++j)
                        acc[i][j] = fmaf(av[i], wv[j], acc[i][j]);
            }
            __syncthreads();
        }
        #pragma unroll
        for (int i = 0; i < 4; ++i)
            #pragma unroll
            for (int j = 0; j < 4; ++j)
                m1buf[tc * 4 + i][tr * 4 + j] = lrelu(acc[i][j]);
        __syncthreads();
        if (tid < 128) {
            float m3 = bm3[0];
            #pragma unroll 2
            for (int j = 0; j < 16; ++j) {
                float s = bm2[j];
                #pragma unroll
                for (int k = 0; k < 32; ++k)
                    s = fmaf(Wm2[j * 32 + k], m1buf[tid][k], s);
                m3 = fmaf(Wm3[j], lrelu(s), m3);
            }
            out[NPIX + q0 + tid] = lrelu(m3);
        }
        return;
    }

    // ---------------- GEMM path (x_t / r_t) ----------------
    const float* __restrict__ W    = (blockIdx.y == 0) ? Wcl1 : Wr1;
    const float* __restrict__ bias = (blockIdx.y == 0) ? bcl1 : br1;
    float* __restrict__ outp       = (blockIdx.y == 0) ? x_t : r_t;

    const int tc = tid & 15;
    const int tr = tid >> 4;

    float acc[8][8];
    #pragma unroll
    for (int i = 0; i < 8; ++i)
        #pragma unroll
        for (int j = 0; j < 8; ++j)
            acc[i][j] = bias[(j >> 2) * 64 + tr * 4 + (j & 3)];

    for (int k0 = 0; k0 < 128; k0 += 16) {
        #pragma unroll
        for (int p = 0; p < 2; ++p) {
            int lin = p * 1024 + tid * 4;
            int kk = lin >> 7, px = lin & 127;
            float4 v = *(const float4*)(X + (k0 + kk) * NPIX + q0 + px);
            *(float4*)(&As[kk][px]) = v;
        }
        #pragma unroll
        for (int p = 0; p < 2; ++p) {
            int lin = p * 1024 + tid * 4;
            int row = lin >> 4, kc = lin & 15;
            float4 v = *(const float4*)(W + row * 128 + k0 + kc);
            Ws[kc + 0][row] = v.x; Ws[kc + 1][row] = v.y;
            Ws[kc + 2][row] = v.z; Ws[kc + 3][row] = v.w;
        }
        __syncthreads();
        #pragma unroll
        for (int kk = 0; kk < 16; ++kk) {
            float4 a0 = *(const float4*)(&As[kk][tc * 4]);
            float4 a1 = *(const float4*)(&As[kk][64 + tc * 4]);
            float4 w0 = *(const float4*)(&Ws[kk][tr * 4]);
            float4 w1 = *(const float4*)(&Ws[kk][64 + tr * 4]);
            float av[8] = {a0.x,a0.y,a0.z,a0.w,a1.x,a1.y,a1.z,a1.w};
            float wv[8] = {w0.x,w0.y,w0.z,w0.w,w1.x,w1.y,w1.z,w1.w};
            #pragma unroll
            for (int i = 0; i < 8; ++i)
                #pragma unroll
                for (int j = 0; j < 8; ++j)
                    acc[i][j] = fmaf(av[i], wv[j], acc[i][j]);
        }
        __syncthreads();
    }

    #pragma unroll
    for (int i = 0; i < 8; ++i) {
        int px = (i >> 2) * 64 + tc * 4 + (i & 3);
        int q  = q0 + px;
        int np = (q & 255) * 192 + (q >> 8);
        float* op = outp + (size_t)np * 128;
        #pragma unroll
        for (int jg = 0; jg < 2; ++jg) {
            float4 o;
            o.x = lrelu(acc[i][jg*4+0]); o.y = lrelu(acc[i][jg*4+1]);
            o.z = lrelu(acc[i][jg*4+2]); o.w = lrelu(acc[i][jg*4+3]);
            *(float4*)(op + jg * 64 + tr * 4) = o;
        }
    }
}

// ============================================================================
// k1b: x2 = lrelu(Wcl21@x), cl1 = Wcl31@x2 + argmax -> inds1_q (q-order).
// ============================================================================
__global__ __launch_bounds__(256, 2) void k1b(
    const float* __restrict__ x_t,
    const float* __restrict__ Wcl21, const float* __restrict__ bcl21,
    const float* __restrict__ Wcl31, const float* __restrict__ bcl31,
    int* __restrict__ inds1_q)
{
    __shared__ float smem[12672];
    float (*As)[132]     = (float(*)[132])smem;
    float (*Ws)[132]     = (float(*)[132])(smem + 2112);
    float (*W31)[132]    = (float(*)[132])smem;
    float (*x2t)[132]    = (float(*)[132])(smem + 4224);
    float (*cl1buf)[33]  = (float(*)[33]) (smem + 4224);

    const int tid = threadIdx.x;
    const int n0  = blockIdx.x * 128;
    const int tcA = tid & 15, trA = tid >> 4;
    const int tcB = tid & 31, trB = tid >> 5;

    float accB[4][4];
    #pragma unroll
    for (int i = 0; i < 4; ++i)
        #pragma unroll
        for (int j = 0; j < 4; ++j)
            accB[i][j] = bcl31[trB * 4 + j];

    for (int h = 0; h < 2; ++h) {
        float acc2[2][4][4];
        #pragma unroll
        for (int gi = 0; gi < 2; ++gi)
            #pragma unroll
            for (int i = 0; i < 4; ++i)
                #pragma unroll
                for (int j = 0; j < 4; ++j)
                    acc2[gi][i][j] = bcl21[h * 64 + trA * 4 + j];

        for (int k0 = 0; k0 < 128; k0 += 16) {
            #pragma unroll
            for (int p = 0; p < 2; ++p) {
                int lin = p * 1024 + tid * 4;
                int px = lin >> 4, kc = lin & 15;
                float4 v = *(const float4*)(x_t + (size_t)(n0 + px) * 128 + k0 + kc);
                As[kc + 0][px] = v.x; As[kc + 1][px] = v.y;
                As[kc + 2][px] = v.z; As[kc + 3][px] = v.w;
            }
            {
                int r = tid >> 2, kc = (tid & 3) * 4;
                float4 v = *(const float4*)(Wcl21 + (h * 64 + r) * 128 + k0 + kc);
                Ws[kc + 0][r] = v.x; Ws[kc + 1][r] = v.y;
                Ws[kc + 2][r] = v.z; Ws[kc + 3][r] = v.w;
            }
            __syncthreads();
            #pragma unroll
            for (int kk = 0; kk < 16; ++kk) {
                float4 a0 = *(const float4*)(&As[kk][tcA * 4]);
                float4 a1 = *(const float4*)(&As[kk][64 + tcA * 4]);
                float4 w  = *(const float4*)(&Ws[kk][trA * 4]);
                float av0[4] = {a0.x,a0.y,a0.z,a0.w};
                float av1[4] = {a1.x,a1.y,a1.z,a1.w};
                float wv[4]  = {w.x,w.y,w.z,w.w};
                #pragma unroll
                for (int i = 0; i < 4; ++i)
                    #pragma unroll
                    for (int j = 0; j < 4; ++j) {
                        acc2[0][i][j] = fmaf(av0[i], wv[j], acc2[0][i][j]);
                        acc2[1][i][j] = fmaf(av1[i], wv[j], acc2[1][i][j]);
                    }
            }
            __syncthreads();
        }
        #pragma unroll
        for (int j = 0; j < 4; ++j) {
            int row = trA * 4 + j;
            #pragma unroll
            for (int gi = 0; gi < 2; ++gi) {
                float4 o;
                o.x = lrelu(acc2[gi][0][j]); o.y = lrelu(acc2[gi][1][j]);
                o.z = lrelu(acc2[gi][2][j]); o.w = lrelu(acc2[gi][3][j]);
                *(float4*)(&x2t[row][gi * 64 + tcA * 4]) = o;
            }
        }
        __syncthreads();
        #pragma unroll
        for (int p = 0; p < 4; ++p) {
            int lin = p * 1024 + tid * 4;
            int row = lin >> 7, kc = lin & 127;
            *(float4*)(&W31[row][kc]) = *(const float4*)(Wcl31 + row * 128 + kc);
        }
        __syncthreads();
        for (int k = 0; k < 64; ++k) {
            float4 a = *(const float4*)(&x2t[k][tcB * 4]);
            float av[4] = {a.x,a.y,a.z,a.w};
            float wv[4];
            #pragma unroll
            for (int j = 0; j < 4; ++j) wv[j] = W31[trB * 4 + j][h * 64 + k];
            #pragma unroll
            for (int i = 0; i < 4; ++i)
                #pragma unroll
                for (int j = 0; j < 4; ++j)
                    accB[i][j] = fmaf(av[i], wv[j], accB[i][j]);
        }
        __syncthreads();
    }

    #pragma unroll
    for (int i = 0; i < 4; ++i)
        #pragma unroll
        for (int j = 0; j < 4; ++j)
            cl1buf[tcB * 4 + i][trB * 4 + j] = accB[i][j];
    __syncthreads();
    if (tid < 128) {
        float bv = cl1buf[tid][0]; int bi = 0;
        #pragma unroll
        for (int c = 1; c < 32; ++c) {
            float v = cl1buf[tid][c];
            if (v > bv) { bv = v; bi = c; }
        }
        int n = n0 + tid;
        int w = n / 192, hh = n - w * 192;
        inds1_q[hh * 256 + w] = bi;
    }
}

// ============================================================================
// k_histscan: 32 blocks (one per class). Per-64-seg counts via ballot over
// ALL 768 segments (192 iters x 4 waves), block-scan -> ebb + total[k].
// ============================================================================
__global__ void k_histscan(const int* __restrict__ inds1_q,
                           int* __restrict__ ebb, int* __restrict__ total)
{
    __shared__ int segcnt[NSEG];
    __shared__ int ssum[256];
    const int k = blockIdx.x;
    const int tid = threadIdx.x;
    const int lane = tid & 63;
    const int wv = tid >> 6;

    for (int c = 0; c < NSEG / 4; ++c) {          // 192 iters: seg 0..767
        int seg = c * 4 + wv;
        int key = inds1_q[seg * 64 + lane];
        unsigned long long m = __ballot(key == k);
        if (lane == 0) segcnt[seg] = __popcll(m);
    }
    __syncthreads();
    int v0 = segcnt[tid * 3 + 0];
    int v1 = segcnt[tid * 3 + 1];
    int v2 = segcnt[tid * 3 + 2];
    int sum = v0 + v1 + v2;
    ssum[tid] = sum; __syncthreads();
    for (int d = 1; d < 256; d <<= 1) {
        int x = (tid >= d) ? ssum[tid - d] : 0;
        __syncthreads();
        ssum[tid] += x;
        __syncthreads();
    }
    int ex = ssum[tid] - sum;
    ebb[(tid * 3 + 0) * 32 + k] = ex;
    ebb[(tid * 3 + 1) * 32 + k] = ex + v0;
    ebb[(tid * 3 + 2) * 32 + k] = ex + v0 + v1;
    if (tid == 255) total[k] = ssum[255];
}

// ============================================================================
// k_scatter2: deterministic rank scatter; class bases computed locally.
// ============================================================================
__global__ void k_scatter2(const int* __restrict__ inds1_q,
                           const int* __restrict__ ebb,
                           const int* __restrict__ total,
                           int* __restrict__ order)
{
    __shared__ int ttot[32];
    const int tid = threadIdx.x;
    if (tid < 32) ttot[tid] = total[tid];
    __syncthreads();
    int n = blockIdx.x * 256 + tid;
    int key = inds1_q[n];
    int lane = tid & 63;
    unsigned long long peers = 0;
    for (int k = 0; k < 32; ++k) {
        unsigned long long m = __ballot(key == k);
        if (key == k) peers = m;
    }
    int rank = __popcll(peers & ((1ull << lane) - 1ull));
    int cbase = 0;
    #pragma unroll
    for (int k = 0; k < 32; ++k) cbase += (k < key) ? ttot[k] : 0;
    order[cbase + ebb[(n >> 6) * 32 + key] + rank] = n;
}

// ============================================================================
// k2b v3: per-chunk (64 px, class-uniform) GEMM micro-kernel.
// LDS 64,904 B; redv/redi alias Hs (temporally disjoint). Weights staged via
// coalesced float4 copies; hot loops = ds_read_b128/b64 + FMA, no in-loop
// s_loads.
// ============================================================================
__global__ __launch_bounds__(256, 2) void k2b(
    const float* __restrict__ x_t, const float* __restrict__ r_t,
    const float* __restrict__ Wcl22, const float* __restrict__ bcl22,
    const float* __restrict__ Wcl32, const float* __restrict__ bcl32,
    const float* __restrict__ Wr2,  const float* __restrict__ br2,
    const float* __restrict__ Wr3,  const float* __restrict__ br3,
    const int* __restrict__ total, const int* __restrict__ order,
    float* __restrict__ out)
{
    __shared__ float Xs[128][68];    // X then R          (34816 B)
    __shared__ float Wks[128 * 32];  // Wa then Wc        (16384 B)
    __shared__ float Wbs[32 * 32];   // Wb                 (4096 B)
    __shared__ float HsU[2176];      // Hs[32][68] | redv[16][68]+redi[16][68]
    __shared__ int   ns[64];
    __shared__ int   indbuf[64];
    __shared__ int   cpre[33];
    __shared__ int   cbase[33];
    __shared__ int   ttot[32];

    float (*Hs)[68]   = (float(*)[68])HsU;
    float (*redv)[68] = (float(*)[68])HsU;
    int   (*redi)[68] = (int(*)[68])(HsU + 1088);

    const int tid = threadIdx.x;
    const int tc  = tid & 15;        // px = tc*4 + pi
    const int tr  = tid >> 4;        // out = tr*2 + oi   (tr 0..15)
    const int row = tid >> 2;        // staging: 4 lanes/row
    const int part = tid & 3;

    if (tid < 32) ttot[tid] = total[tid];
    __syncthreads();
    if (tid == 0) {
        int s = 0, cb = 0;
        for (int k = 0; k < 32; ++k) {
            cpre[k] = s; cbase[k] = cb;
            int c = ttot[k];
            s += (c + 63) >> 6;
            cb += c;
        }
        cpre[32] = s; cbase[32] = cb;
    }
    __syncthreads();
    const int nchunks = cpre[32];

    for (int ci = blockIdx.x; ci < nchunks; ci += gridDim.x) {
        int cls = 0;
        while (cpre[cls + 1] <= ci) ++cls;
        const int st   = (ci - cpre[cls]) * 64;
        const int cnt  = ttot[cls];
        const int npx  = min(64, cnt - st);
        const int base = cbase[cls] + st;

        if (tid < 64) ns[tid] = order[base + min(tid, npx - 1)];
        // stage Wa [128][32] and Wb [32][32]
        {
            const float4* wsrc = (const float4*)(Wcl22 + cls * 4096);
            float4* wdst = (float4*)Wks;
            #pragma unroll
            for (int j = 0; j < 4; ++j) wdst[j * 256 + tid] = wsrc[j * 256 + tid];
            ((float4*)Wbs)[tid] = ((const float4*)(Wcl32 + cls * 1024))[tid];
        }
        __syncthreads();   // B1: ns/Wks/Wbs ready
        // stage X (4 lanes x 16B per gathered row)
        {
            const float* src = x_t + (size_t)ns[row] * 128;
            #pragma unroll
            for (int j = 0; j < 8; ++j) {
                int c = j * 16 + part * 4;
                float4 v = *(const float4*)(src + c);
                Xs[c+0][row] = v.x; Xs[c+1][row] = v.y;
                Xs[c+2][row] = v.z; Xs[c+3][row] = v.w;
            }
        }
        __syncthreads();   // B2: Xs ready

        // ---- h GEMM: K=128 ----
        float ha[4][2];
        {
            float b0 = bcl22[cls * 32 + tr * 2];
            float b1 = bcl22[cls * 32 + tr * 2 + 1];
            #pragma unroll
            for (int pi = 0; pi < 4; ++pi) { ha[pi][0] = b0; ha[pi][1] = b1; }
        }
        #pragma unroll 4
        for (int k = 0; k < 128; ++k) {
            float4 a = *(const float4*)(&Xs[k][tc * 4]);
            float2 b = *(const float2*)(&Wks[k * 32 + tr * 2]);
            float av[4] = {a.x, a.y, a.z, a.w};
            #pragma unroll
            for (int pi = 0; pi < 4; ++pi) {
                ha[pi][0] = fmaf(av[pi], b.x, ha[pi][0]);
                ha[pi][1] = fmaf(av[pi], b.y, ha[pi][1]);
            }
        }
        #pragma unroll
        for (int pi = 0; pi < 4; ++pi) {
            Hs[tr * 2 + 0][tc * 4 + pi] = lrelu(ha[pi][0]);
            Hs[tr * 2 + 1][tc * 4 + pi] = lrelu(ha[pi][1]);
        }
        __syncthreads();   // B3: Hs ready

        // ---- g GEMM (K=32)  +  global prefetch of Wc and R into registers ----
        float4 wcbuf[4];
        float4 rbuf[8];
        {
            const float4* wsrc = (const float4*)(Wr2 + (cls >> 2) * 4096);
            #pragma unroll
            for (int j = 0; j < 4; ++j) wcbuf[j] = wsrc[j * 256 + tid];
            const float* src = r_t + (size_t)ns[row] * 128;
            #pragma unroll
            for (int j = 0; j < 8; ++j)
                rbuf[j] = *(const float4*)(src + j * 16 + part * 4);
        }
        float ga[4][2];
        {
            float b0 = bcl32[cls * 32 + tr * 2];
            float b1 = bcl32[cls * 32 + tr * 2 + 1];
            #pragma unroll
            for (int pi = 0; pi < 4; ++pi) { ga[pi][0] = b0; ga[pi][1] = b1; }
        }
        #pragma unroll 4
        for (int k = 0; k < 32; ++k) {
            float4 a = *(const float4*)(&Hs[k][tc * 4]);
            float2 b = *(const float2*)(&Wbs[k * 32 + tr * 2]);
            float av[4] = {a.x, a.y, a.z, a.w};
            #pragma unroll
            for (int pi = 0; pi < 4; ++pi) {
                ga[pi][0] = fmaf(av[pi], b.x, ga[pi][0]);
                ga[pi][1] = fmaf(av[pi], b.y, ga[pi][1]);
            }
        }
        __syncthreads();   // B4: all Hs reads done -> redv/redi may alias it

        // per-thread argmax candidates (channels tr*2, tr*2+1; first-max wins)
        #pragma unroll
        for (int pi = 0; pi < 4; ++pi) {
            float bv = ga[pi][0]; int bi = tr * 2;
            if (ga[pi][1] > bv) { bv = ga[pi][1]; bi = tr * 2 + 1; }
            redv[tr][tc * 4 + pi] = bv;
            redi[tr][tc * 4 + pi] = bi;
        }
        // commit staged Wc / R
        {
            float4* wdst = (float4*)Wks;
            #pragma unroll
            for (int j = 0; j < 4; ++j) wdst[j * 256 + tid] = wcbuf[j];
            #pragma unroll
            for (int j = 0; j < 8; ++j) {
                int c = j * 16 + part * 4;
                Xs[c+0][row] = rbuf[j].x; Xs[c+1][row] = rbuf[j].y;
                Xs[c+2][row] = rbuf[j].z; Xs[c+3][row] = rbuf[j].w;
            }
        }
        __syncthreads();   // B5: redv/redi + R/Wc ready

        // ---- argmax finalize (wave 0) || r2 GEMM (all threads) ----
        if (tid < 64) {
            float bv = redv[0][tid]; int bi = redi[0][tid];
            #pragma unroll
            for (int t = 1; t < 16; ++t) {      // ascending t = ascending channel
                float v = redv[t][tid];
                if (v > bv) { bv = v; bi = redi[t][tid]; }
            }
            indbuf[tid] = cls * 32 + bi;
        }
        float ra[4][2];
        {
            float b0 = br2[(cls >> 2) * 32 + tr * 2];
            float b1 = br2[(cls >> 2) * 32 + tr * 2 + 1];
            #pragma unroll
            for (int pi = 0; pi < 4; ++pi) { ra[pi][0] = b0; ra[pi][1] = b1; }
        }
        #pragma unroll 4
        for (int k = 0; k < 128; ++k) {
            float4 a = *(const float4*)(&Xs[k][tc * 4]);
            float2 b = *(const float2*)(&Wks[k * 32 + tr * 2]);
            float av[4] = {a.x, a.y, a.z, a.w};
            #pragma unroll
            for (int pi = 0; pi < 4; ++pi) {
                ra[pi][0] = fmaf(av[pi], b.x, ra[pi][0]);
                ra[pi][1] = fmaf(av[pi], b.y, ra[pi][1]);
            }
        }
        __syncthreads();   // B6: indbuf visible; redv reads (wave0) done

        // ---- partial dot with Wr3[ind] ----
        #pragma unroll
        for (int pi = 0; pi < 4; ++pi) {
            int ind = indbuf[tc * 4 + pi];
            float2 w = *(const float2*)(Wr3 + ind * 32 + tr * 2);
            redv[tr][tc * 4 + pi] = lrelu(ra[pi][0]) * w.x + lrelu(ra[pi][1]) * w.y;
        }
        __syncthreads();   // B7
        if (tid < npx) {
            int ind = indbuf[tid];
            float reg = br3[ind];
            #pragma unroll
            for (int t = 0; t < 16; ++t) reg += redv[t][tid];
            out[ns[tid]] = ((float)ind + reg) * (1.0f / 1024.0f);
        }
        __syncthreads();   // B8: end of chunk
    }
}

extern "C" void kernel_launch(void* const* d_in, const int* in_sizes, int n_in,
                              void* d_out, int out_size, void* d_ws, size_t ws_size,
                              hipStream_t stream)
{
    const float* X     = (const float*)d_in[0];
    const float* Wm1   = (const float*)d_in[1];
    const float* bm1   = (const float*)d_in[2];
    const float* Wm2   = (const float*)d_in[3];
    const float* bm2   = (const float*)d_in[4];
    const float* Wm3   = (const float*)d_in[5];
    const float* bm3   = (const float*)d_in[6];
    const float* Wcl1  = (const float*)d_in[7];
    const float* bcl1  = (const float*)d_in[8];
    const float* Wcl21 = (const float*)d_in[9];
    const float* bcl21 = (const float*)d_in[10];
    const float* Wcl31 = (const float*)d_in[11];
    const float* bcl31 = (const float*)d_in[12];
    const float* Wcl22 = (const float*)d_in[13];
    const float* bcl22 = (const float*)d_in[14];
    const float* Wcl32 = (const float*)d_in[15];
    const float* bcl32 = (const float*)d_in[16];
    const float* Wr1   = (const float*)d_in[17];
    const float* br1   = (const float*)d_in[18];
    const float* Wr2   = (const float*)d_in[19];
    const float* br2   = (const float*)d_in[20];
    const float* Wr3   = (const float*)d_in[21];
    const float* br3   = (const float*)d_in[22];
    float* out = (float*)d_out;

    float* x_t   = (float*)d_ws;
    float* r_t   = x_t + (size_t)NPIX * 128;
    int* inds1_q = (int*)(r_t + (size_t)NPIX * 128);
    int* order   = inds1_q + NPIX;
    int* ebb     = order + NPIX;        // [768][32]
    int* total   = ebb + NSEG * 32;     // [32]

    k_fused1<<<dim3(NPIX / 128, 3), 256, 0, stream>>>(X, Wcl1, bcl1, Wr1, br1,
                                                      Wm1, bm1, Wm2, bm2, Wm3, bm3,
                                                      x_t, r_t, out);
    k1b<<<NPIX / 128, 256, 0, stream>>>(x_t, Wcl21, bcl21, Wcl31, bcl31, inds1_q);
    k_histscan<<<32, 256, 0, stream>>>(inds1_q, ebb, total);
    k_scatter2<<<NPIX / 256, 256, 0, stream>>>(inds1_q, ebb, total, order);
    k2b<<<512, 256, 0, stream>>>(x_t, r_t, Wcl22, bcl22, Wcl32, bcl32,
                                 Wr2, br2, Wr3, br3, total, order, out);
}

// Round 7
// 247.730 us; speedup vs baseline: 1.2112x; 1.2112x over previous
//
#include <hip/hip_runtime.h>

#define HH 192
#define WW 256
#define NPIX (HH*WW)   // 49152
#define NSEG (NPIX/64) // 768

__device__ __forceinline__ float lrelu(float v) { return v > 0.0f ? v : 0.01f * v; }

// ============================================================================
// k_fused1: y=0 -> x_t = lrelu(Wcl1@X)^T-stored; y=1 -> r_t (Wr1);
//           y=2 -> full mask branch.   (unchanged from R6, passing)
// ============================================================================
__global__ __launch_bounds__(256, 3) void k_fused1(
    const float* __restrict__ X,
    const float* __restrict__ Wcl1, const float* __restrict__ bcl1,
    const float* __restrict__ Wr1,  const float* __restrict__ br1,
    const float* __restrict__ Wm1,  const float* __restrict__ bm1,
    const float* __restrict__ Wm2,  const float* __restrict__ bm2,
    const float* __restrict__ Wm3,  const float* __restrict__ bm3,
    float* __restrict__ x_t, float* __restrict__ r_t,
    float* __restrict__ out)
{
    __shared__ float As[16][132];
    __shared__ float Ws[16][132];
    __shared__ float m1buf[128][33];
    const int tid = threadIdx.x;
    const int q0  = blockIdx.x * 128;

    if (blockIdx.y == 2) {
        const int tc = tid & 31;
        const int tr = tid >> 5;
        float acc[4][4];
        #pragma unroll
        for (int i = 0; i < 4; ++i)
            #pragma unroll
            for (int j = 0; j < 4; ++j)
                acc[i][j] = bm1[tr * 4 + j];

        for (int k0 = 0; k0 < 128; k0 += 16) {
            #pragma unroll
            for (int p = 0; p < 2; ++p) {
                int lin = p * 1024 + tid * 4;
                int kk = lin >> 7, px = lin & 127;
                float4 v = *(const float4*)(X + (k0 + kk) * NPIX + q0 + px);
                *(float4*)(&As[kk][px]) = v;
            }
            if (tid < 128) {
                int row = tid >> 2, kc = (tid & 3) * 4;
                float4 v = *(const float4*)(Wm1 + row * 128 + k0 + kc);
                Ws[kc + 0][row] = v.x; Ws[kc + 1][row] = v.y;
                Ws[kc + 2][row] = v.z; Ws[kc + 3][row] = v.w;
            }
            __syncthreads();
            #pragma unroll
            for (int kk = 0; kk < 16; ++kk) {
                float4 a = *(const float4*)(&As[kk][tc * 4]);
                float4 w = *(const float4*)(&Ws[kk][tr * 4]);
                float av[4] = {a.x,a.y,a.z,a.w};
                float wv[4] = {w.x,w.y,w.z,w.w};
                #pragma unroll
                for (int i = 0; i < 4; ++i)
                    #pragma unroll
                    for (int j = 0; j < 4; ++j)
                        acc[i][j] = fmaf(av[i], wv[j], acc[i][j]);
            }
            __syncthreads();
        }
        #pragma unroll
        for (int i = 0; i < 4; ++i)
            #pragma unroll
            for (int j = 0; j < 4; ++j)
                m1buf[tc * 4 + i][tr * 4 + j] = lrelu(acc[i][j]);
        __syncthreads();
        if (tid < 128) {
            float m3 = bm3[0];
            #pragma unroll 2
            for (int j = 0; j < 16; ++j) {
                float s = bm2[j];
                #pragma unroll
                for (int k = 0; k < 32; ++k)
                    s = fmaf(Wm2[j * 32 + k], m1buf[tid][k], s);
                m3 = fmaf(Wm3[j], lrelu(s), m3);
            }
            out[NPIX + q0 + tid] = lrelu(m3);
        }
        return;
    }

    const float* __restrict__ W    = (blockIdx.y == 0) ? Wcl1 : Wr1;
    const float* __restrict__ bias = (blockIdx.y == 0) ? bcl1 : br1;
    float* __restrict__ outp       = (blockIdx.y == 0) ? x_t : r_t;

    const int tc = tid & 15;
    const int tr = tid >> 4;

    float acc[8][8];
    #pragma unroll
    for (int i = 0; i < 8; ++i)
        #pragma unroll
        for (int j = 0; j < 8; ++j)
            acc[i][j] = bias[(j >> 2) * 64 + tr * 4 + (j & 3)];

    for (int k0 = 0; k0 < 128; k0 += 16) {
        #pragma unroll
        for (int p = 0; p < 2; ++p) {
            int lin = p * 1024 + tid * 4;
            int kk = lin >> 7, px = lin & 127;
            float4 v = *(const float4*)(X + (k0 + kk) * NPIX + q0 + px);
            *(float4*)(&As[kk][px]) = v;
        }
        #pragma unroll
        for (int p = 0; p < 2; ++p) {
            int lin = p * 1024 + tid * 4;
            int row = lin >> 4, kc = lin & 15;
            float4 v = *(const float4*)(W + row * 128 + k0 + kc);
            Ws[kc + 0][row] = v.x; Ws[kc + 1][row] = v.y;
            Ws[kc + 2][row] = v.z; Ws[kc + 3][row] = v.w;
        }
        __syncthreads();
        #pragma unroll
        for (int kk = 0; kk < 16; ++kk) {
            float4 a0 = *(const float4*)(&As[kk][tc * 4]);
            float4 a1 = *(const float4*)(&As[kk][64 + tc * 4]);
            float4 w0 = *(const float4*)(&Ws[kk][tr * 4]);
            float4 w1 = *(const float4*)(&Ws[kk][64 + tr * 4]);
            float av[8] = {a0.x,a0.y,a0.z,a0.w,a1.x,a1.y,a1.z,a1.w};
            float wv[8] = {w0.x,w0.y,w0.z,w0.w,w1.x,w1.y,w1.z,w1.w};
            #pragma unroll
            for (int i = 0; i < 8; ++i)
                #pragma unroll
                for (int j = 0; j < 8; ++j)
                    acc[i][j] = fmaf(av[i], wv[j], acc[i][j]);
        }
        __syncthreads();
    }

    #pragma unroll
    for (int i = 0; i < 8; ++i) {
        int px = (i >> 2) * 64 + tc * 4 + (i & 3);
        int q  = q0 + px;
        int np = (q & 255) * 192 + (q >> 8);
        float* op = outp + (size_t)np * 128;
        #pragma unroll
        for (int jg = 0; jg < 2; ++jg) {
            float4 o;
            o.x = lrelu(acc[i][jg*4+0]); o.y = lrelu(acc[i][jg*4+1]);
            o.z = lrelu(acc[i][jg*4+2]); o.w = lrelu(acc[i][jg*4+3]);
            *(float4*)(op + jg * 64 + tr * 4) = o;
        }
    }
}

// ============================================================================
// k1b: x2 = lrelu(Wcl21@x), cl1 = Wcl31@x2 + argmax -> inds1_q (q-order).
// (unchanged from R6, passing)
// ============================================================================
__global__ __launch_bounds__(256, 2) void k1b(
    const float* __restrict__ x_t,
    const float* __restrict__ Wcl21, const float* __restrict__ bcl21,
    const float* __restrict__ Wcl31, const float* __restrict__ bcl31,
    int* __restrict__ inds1_q)
{
    __shared__ float smem[12672];
    float (*As)[132]     = (float(*)[132])smem;
    float (*Ws)[132]     = (float(*)[132])(smem + 2112);
    float (*W31)[132]    = (float(*)[132])smem;
    float (*x2t)[132]    = (float(*)[132])(smem + 4224);
    float (*cl1buf)[33]  = (float(*)[33]) (smem + 4224);

    const int tid = threadIdx.x;
    const int n0  = blockIdx.x * 128;
    const int tcA = tid & 15, trA = tid >> 4;
    const int tcB = tid & 31, trB = tid >> 5;

    float accB[4][4];
    #pragma unroll
    for (int i = 0; i < 4; ++i)
        #pragma unroll
        for (int j = 0; j < 4; ++j)
            accB[i][j] = bcl31[trB * 4 + j];

    for (int h = 0; h < 2; ++h) {
        float acc2[2][4][4];
        #pragma unroll
        for (int gi = 0; gi < 2; ++gi)
            #pragma unroll
            for (int i = 0; i < 4; ++i)
                #pragma unroll
                for (int j = 0; j < 4; ++j)
                    acc2[gi][i][j] = bcl21[h * 64 + trA * 4 + j];

        for (int k0 = 0; k0 < 128; k0 += 16) {
            #pragma unroll
            for (int p = 0; p < 2; ++p) {
                int lin = p * 1024 + tid * 4;
                int px = lin >> 4, kc = lin & 15;
                float4 v = *(const float4*)(x_t + (size_t)(n0 + px) * 128 + k0 + kc);
                As[kc + 0][px] = v.x; As[kc + 1][px] = v.y;
                As[kc + 2][px] = v.z; As[kc + 3][px] = v.w;
            }
            {
                int r = tid >> 2, kc = (tid & 3) * 4;
                float4 v = *(const float4*)(Wcl21 + (h * 64 + r) * 128 + k0 + kc);
                Ws[kc + 0][r] = v.x; Ws[kc + 1][r] = v.y;
                Ws[kc + 2][r] = v.z; Ws[kc + 3][r] = v.w;
            }
            __syncthreads();
            #pragma unroll
            for (int kk = 0; kk < 16; ++kk) {
                float4 a0 = *(const float4*)(&As[kk][tcA * 4]);
                float4 a1 = *(const float4*)(&As[kk][64 + tcA * 4]);
                float4 w  = *(const float4*)(&Ws[kk][trA * 4]);
                float av0[4] = {a0.x,a0.y,a0.z,a0.w};
                float av1[4] = {a1.x,a1.y,a1.z,a1.w};
                float wv[4]  = {w.x,w.y,w.z,w.w};
                #pragma unroll
                for (int i = 0; i < 4; ++i)
                    #pragma unroll
                    for (int j = 0; j < 4; ++j) {
                        acc2[0][i][j] = fmaf(av0[i], wv[j], acc2[0][i][j]);
                        acc2[1][i][j] = fmaf(av1[i], wv[j], acc2[1][i][j]);
                    }
            }
            __syncthreads();
        }
        #pragma unroll
        for (int j = 0; j < 4; ++j) {
            int row = trA * 4 + j;
            #pragma unroll
            for (int gi = 0; gi < 2; ++gi) {
                float4 o;
                o.x = lrelu(acc2[gi][0][j]); o.y = lrelu(acc2[gi][1][j]);
                o.z = lrelu(acc2[gi][2][j]); o.w = lrelu(acc2[gi][3][j]);
                *(float4*)(&x2t[row][gi * 64 + tcA * 4]) = o;
            }
        }
        __syncthreads();
        #pragma unroll
        for (int p = 0; p < 4; ++p) {
            int lin = p * 1024 + tid * 4;
            int row = lin >> 7, kc = lin & 127;
            *(float4*)(&W31[row][kc]) = *(const float4*)(Wcl31 + row * 128 + kc);
        }
        __syncthreads();
        for (int k = 0; k < 64; ++k) {
            float4 a = *(const float4*)(&x2t[k][tcB * 4]);
            float av[4] = {a.x,a.y,a.z,a.w};
            float wv[4];
            #pragma unroll
            for (int j = 0; j < 4; ++j) wv[j] = W31[trB * 4 + j][h * 64 + k];
            #pragma unroll
            for (int i = 0; i < 4; ++i)
                #pragma unroll
                for (int j = 0; j < 4; ++j)
                    accB[i][j] = fmaf(av[i], wv[j], accB[i][j]);
        }
        __syncthreads();
    }

    #pragma unroll
    for (int i = 0; i < 4; ++i)
        #pragma unroll
        for (int j = 0; j < 4; ++j)
            cl1buf[tcB * 4 + i][trB * 4 + j] = accB[i][j];
    __syncthreads();
    if (tid < 128) {
        float bv = cl1buf[tid][0]; int bi = 0;
        #pragma unroll
        for (int c = 1; c < 32; ++c) {
            float v = cl1buf[tid][c];
            if (v > bv) { bv = v; bi = c; }
        }
        int n = n0 + tid;
        int w = n / 192, hh = n - w * 192;
        inds1_q[hh * 256 + w] = bi;
    }
}

// ============================================================================
// k_hist (R2, passing): 192 blocks; per-64-seg ballot histogram -> bh[seg][32]
// ============================================================================
__global__ void k_hist(const int* __restrict__ inds1_q, int* __restrict__ bh) {
    int tid = threadIdx.x;
    int n = blockIdx.x * 256 + tid;
    int key = inds1_q[n];
    int lane = tid & 63;
    int cnt = 0;
    for (int k = 0; k < 32; ++k) {
        unsigned long long m = __ballot(key == k);
        if (lane == k) cnt = __popcll(m);
    }
    if (lane < 32) bh[(n >> 6) * 32 + lane] = cnt;
}

// ============================================================================
// k_scanA (R2, passing): 32 blocks (class each); scan 768 seg counts -> ebb,
// total[k].
// ============================================================================
__global__ void k_scanA(const int* __restrict__ bh, int* __restrict__ ebb,
                        int* __restrict__ total) {
    __shared__ int s[256];
    const int k = blockIdx.x, t = threadIdx.x;
    int v0 = bh[(t * 3 + 0) * 32 + k];
    int v1 = bh[(t * 3 + 1) * 32 + k];
    int v2 = bh[(t * 3 + 2) * 32 + k];
    int sum = v0 + v1 + v2;
    s[t] = sum; __syncthreads();
    for (int d = 1; d < 256; d <<= 1) {
        int x = (t >= d) ? s[t - d] : 0;
        __syncthreads();
        s[t] += x;
        __syncthreads();
    }
    int ex = s[t] - sum;
    ebb[(t * 3 + 0) * 32 + k] = ex;
    ebb[(t * 3 + 1) * 32 + k] = ex + v0;
    ebb[(t * 3 + 2) * 32 + k] = ex + v0 + v1;
    if (t == 255) total[k] = s[255];
}

// ============================================================================
// k_scatter2 (R6, passing): deterministic rank scatter, local class bases.
// ============================================================================
__global__ void k_scatter2(const int* __restrict__ inds1_q,
                           const int* __restrict__ ebb,
                           const int* __restrict__ total,
                           int* __restrict__ order)
{
    __shared__ int ttot[32];
    const int tid = threadIdx.x;
    if (tid < 32) ttot[tid] = total[tid];
    __syncthreads();
    int n = blockIdx.x * 256 + tid;
    int key = inds1_q[n];
    int lane = tid & 63;
    unsigned long long peers = 0;
    for (int k = 0; k < 32; ++k) {
        unsigned long long m = __ballot(key == k);
        if (key == k) peers = m;
    }
    int rank = __popcll(peers & ((1ull << lane) - 1ull));
    int cbase = 0;
    #pragma unroll
    for (int k = 0; k < 32; ++k) cbase += (k < key) ? ttot[k] : 0;
    order[cbase + ebb[(n >> 6) * 32 + key] + rank] = n;
}

// ============================================================================
// k2h: stage-2 first half. One thread = one pixel (256-px class chunks).
// Weights LDS-broadcast; x row streamed per-lane (16B loads fully consume
// lines). h = lrelu(x@Wa+ba); g = h@Wb+bb; per-thread argmax -> ind_ord.
// No barriers in hot loop.
// ============================================================================
__global__ __launch_bounds__(256, 4) void k2h(
    const float* __restrict__ x_t,
    const float* __restrict__ Wcl22, const float* __restrict__ bcl22,
    const float* __restrict__ Wcl32, const float* __restrict__ bcl32,
    const int* __restrict__ total, const int* __restrict__ order,
    int* __restrict__ ind_ord)
{
    __shared__ float Was[4096];
    __shared__ float Wbs[1024];
    __shared__ int cpre[33];
    __shared__ int cbase[33];
    __shared__ int ttot[32];

    const int tid = threadIdx.x;
    if (tid < 32) ttot[tid] = total[tid];
    __syncthreads();
    if (tid == 0) {
        int s = 0, cb = 0;
        for (int k = 0; k < 32; ++k) {
            cpre[k] = s; cbase[k] = cb;
            int c = ttot[k];
            s += (c + 255) >> 8;
            cb += c;
        }
        cpre[32] = s; cbase[32] = cb;
    }
    __syncthreads();
    const int ci = blockIdx.x;
    if (ci >= cpre[32]) return;
    int cls = 0;
    while (cpre[cls + 1] <= ci) ++cls;
    const int st   = (ci - cpre[cls]) * 256;
    const int npx  = min(256, ttot[cls] - st);
    const int base = cbase[cls] + st;

    {
        const float4* ws = (const float4*)(Wcl22 + cls * 4096);
        #pragma unroll
        for (int j = 0; j < 4; ++j) ((float4*)Was)[j * 256 + tid] = ws[j * 256 + tid];
        ((float4*)Wbs)[tid] = ((const float4*)(Wcl32 + cls * 1024))[tid];
    }
    __syncthreads();

    const int m = order[base + min(tid, npx - 1)];
    const float4* xp = (const float4*)(x_t + (size_t)m * 128);

    float h[32];
    #pragma unroll
    for (int j = 0; j < 32; ++j) h[j] = bcl22[cls * 32 + j];
    #pragma unroll 2
    for (int c4 = 0; c4 < 32; ++c4) {
        float4 xv = xp[c4];
        float xa[4] = {xv.x, xv.y, xv.z, xv.w};
        #pragma unroll
        for (int cc = 0; cc < 4; ++cc) {
            const float* wr = &Was[(c4 * 4 + cc) * 32];
            #pragma unroll
            for (int j = 0; j < 32; ++j) h[j] = fmaf(xa[cc], wr[j], h[j]);
        }
    }
    #pragma unroll
    for (int j = 0; j < 32; ++j) h[j] = lrelu(h[j]);

    float g[32];
    #pragma unroll
    for (int j = 0; j < 32; ++j) g[j] = bcl32[cls * 32 + j];
    #pragma unroll 2
    for (int c = 0; c < 32; ++c) {
        float hv = h[c];
        const float* wr = &Wbs[c * 32];
        #pragma unroll
        for (int j = 0; j < 32; ++j) g[j] = fmaf(hv, wr[j], g[j]);
    }
    float bv = g[0]; int bi = 0;
    #pragma unroll
    for (int j = 1; j < 32; ++j)
        if (g[j] > bv) { bv = g[j]; bi = j; }     // strict > = first-max (np.argmax)
    if (tid < npx) ind_ord[base + tid] = cls * 32 + bi;
}

// ============================================================================
// k2r: stage-2 second half. r2 = lrelu(r@Wc+bc) (Wc per superclass, LDS);
// reg = br3[ind] + r2 . Wr3[ind] (per-lane 128B gather, L2-hot);
// out[m] = (ind + reg)/1024.
// ============================================================================
__global__ __launch_bounds__(256, 4) void k2r(
    const float* __restrict__ r_t,
    const float* __restrict__ Wr2,  const float* __restrict__ br2,
    const float* __restrict__ Wr3,  const float* __restrict__ br3,
    const int* __restrict__ total, const int* __restrict__ order,
    const int* __restrict__ ind_ord,
    float* __restrict__ out)
{
    __shared__ float Wcs[4096];
    __shared__ int cpre[33];
    __shared__ int cbase[33];
    __shared__ int ttot[32];

    const int tid = threadIdx.x;
    if (tid < 32) ttot[tid] = total[tid];
    __syncthreads();
    if (tid == 0) {
        int s = 0, cb = 0;
        for (int k = 0; k < 32; ++k) {
            cpre[k] = s; cbase[k] = cb;
            int c = ttot[k];
            s += (c + 255) >> 8;
            cb += c;
        }
        cpre[32] = s; cbase[32] = cb;
    }
    __syncthreads();
    const int ci = blockIdx.x;
    if (ci >= cpre[32]) return;
    int cls = 0;
    while (cpre[cls + 1] <= ci) ++cls;
    const int st   = (ci - cpre[cls]) * 256;
    const int npx  = min(256, ttot[cls] - st);
    const int base = cbase[cls] + st;
    const int sup  = cls >> 2;

    {
        const float4* ws = (const float4*)(Wr2 + sup * 4096);
        #pragma unroll
        for (int j = 0; j < 4; ++j) ((float4*)Wcs)[j * 256 + tid] = ws[j * 256 + tid];
    }
    __syncthreads();

    const int li  = min(tid, npx - 1);
    const int m   = order[base + li];
    const int ind = ind_ord[base + li];
    const float4* rp = (const float4*)(r_t + (size_t)m * 128);

    float r2[32];
    #pragma unroll
    for (int j = 0; j < 32; ++j) r2[j] = br2[sup * 32 + j];
    #pragma unroll 2
    for (int c4 = 0; c4 < 32; ++c4) {
        float4 rv = rp[c4];
        float ra[4] = {rv.x, rv.y, rv.z, rv.w};
        #pragma unroll
        for (int cc = 0; cc < 4; ++cc) {
            const float* wr = &Wcs[(c4 * 4 + cc) * 32];
            #pragma unroll
            for (int j = 0; j < 32; ++j) r2[j] = fmaf(ra[cc], wr[j], r2[j]);
        }
    }

    float reg = br3[ind];
    const float* __restrict__ w3 = Wr3 + ind * 32;
    #pragma unroll
    for (int j = 0; j < 32; ++j) reg = fmaf(lrelu(r2[j]), w3[j], reg);

    if (tid < npx) out[m] = ((float)ind + reg) * (1.0f / 1024.0f);
}

extern "C" void kernel_launch(void* const* d_in, const int* in_sizes, int n_in,
                              void* d_out, int out_size, void* d_ws, size_t ws_size,
                              hipStream_t stream)
{
    const float* X     = (const float*)d_in[0];
    const float* Wm1   = (const float*)d_in[1];
    const float* bm1   = (const float*)d_in[2];
    const float* Wm2   = (const float*)d_in[3];
    const float* bm2   = (const float*)d_in[4];
    const float* Wm3   = (const float*)d_in[5];
    const float* bm3   = (const float*)d_in[6];
    const float* Wcl1  = (const float*)d_in[7];
    const float* bcl1  = (const float*)d_in[8];
    const float* Wcl21 = (const float*)d_in[9];
    const float* bcl21 = (const float*)d_in[10];
    const float* Wcl31 = (const float*)d_in[11];
    const float* bcl31 = (const float*)d_in[12];
    const float* Wcl22 = (const float*)d_in[13];
    const float* bcl22 = (const float*)d_in[14];
    const float* Wcl32 = (const float*)d_in[15];
    const float* bcl32 = (const float*)d_in[16];
    const float* Wr1   = (const float*)d_in[17];
    const float* br1   = (const float*)d_in[18];
    const float* Wr2   = (const float*)d_in[19];
    const float* br2   = (const float*)d_in[20];
    const float* Wr3   = (const float*)d_in[21];
    const float* br3   = (const float*)d_in[22];
    float* out = (float*)d_out;

    float* x_t   = (float*)d_ws;
    float* r_t   = x_t + (size_t)NPIX * 128;
    int* inds1_q = (int*)(r_t + (size_t)NPIX * 128);
    int* order   = inds1_q + NPIX;
    int* ind_ord = order + NPIX;
    int* bh      = ind_ord + NPIX;      // [768][32]
    int* ebb     = bh + NSEG * 32;      // [768][32]
    int* total   = ebb + NSEG * 32;     // [32]

    k_fused1<<<dim3(NPIX / 128, 3), 256, 0, stream>>>(X, Wcl1, bcl1, Wr1, br1,
                                                      Wm1, bm1, Wm2, bm2, Wm3, bm3,
                                                      x_t, r_t, out);
    k1b<<<NPIX / 128, 256, 0, stream>>>(x_t, Wcl21, bcl21, Wcl31, bcl31, inds1_q);
    k_hist<<<NPIX / 256, 256, 0, stream>>>(inds1_q, bh);
    k_scanA<<<32, 256, 0, stream>>>(bh, ebb, total);
    k_scatter2<<<NPIX / 256, 256, 0, stream>>>(inds1_q, ebb, total, order);
    // 256-px chunks: worst case sum ceil = 192 + 31 = 223 -> grid 224 covers all
    k2h<<<224, 256, 0, stream>>>(x_t, Wcl22, bcl22, Wcl32, bcl32, total, order, ind_ord);
    k2r<<<224, 256, 0, stream>>>(r_t, Wr2, br2, Wr3, br3, total, order, ind_ord, out);
}